// Round 1
// baseline (211.908 us; speedup 1.0000x reference)
//
#include <hip/hip_runtime.h>
#include <hip/hip_bf16.h>

// Problem: B=4, L=128, C=1024, D=512, all fp32.
// out[b,l,c] = softmax_c( sum_d V[d]*tanh(wq[b,l,d] + uc[b,c,d]) )
// wq = hidden @ W^T  (scaled by 2*log2e in epilogue)
// uc = (ctx @ U^T + U_b) (scaled by 2*log2e in epilogue)
//
// Pipeline:
//  1) gemm_nt (wq):  [512 x 512]   <- hidden [512,512] x W [512,512]
//  2) gemm_nt (uc):  [4096 x 512]  <- ctx [4096,512] x U [512,512] + U_b
//  3) fused_align:   align[512][1024] = -2 * sum_d V_d*(rcp(exp2(wq'+uc')+1) - 0.5)
//     (== sum_d V_d * tanh(wq+uc)), written into d_out
//  4) softmax_kernel: in-place row softmax over 1024
// Workspace: wq_s 1MB + uc_s 8MB = 9MB in d_ws.

#define DD 512

__device__ __forceinline__ float tanh_term(float x) {
    // x is already (wq+uc)*2*log2(e); returns rcp(e^{2t}+1) where t=wq+uc
    return __builtin_amdgcn_rcpf(__builtin_amdgcn_exp2f(x) + 1.0f);
}

// C[m][n] = (sum_k A[m][k]*B[n][k] + bias[n]) * scale
// tile 128x128, 256 threads, 8x8 micro-tile, K chunk 16. M,N multiples of 128, K mult of 16.
__global__ __launch_bounds__(256) void gemm_nt_kernel(
    const float* __restrict__ A, const float* __restrict__ Bm,
    const float* __restrict__ bias, float* __restrict__ Cout,
    int M, int N, int K, float scale)
{
    __shared__ float As[16][128];
    __shared__ float Bs[16][128];
    const int tid = threadIdx.x;
    const int tx = tid & 15;        // 0..15 -> n micro
    const int ty = tid >> 4;        // 0..15 -> m micro
    const int m0 = blockIdx.y * 128, n0 = blockIdx.x * 128;

    float acc[8][8];
#pragma unroll
    for (int i = 0; i < 8; ++i)
#pragma unroll
        for (int j = 0; j < 8; ++j) acc[i][j] = 0.0f;

    const int kq = (tid & 3) * 4;   // k offset within chunk
    const int r  = tid >> 2;        // 0..63 row
    const float* Ap = A + (size_t)(m0 + r) * K + kq;
    const float* Bp = Bm + (size_t)(n0 + r) * K + kq;

    for (int kc = 0; kc < K; kc += 16) {
        float4 a0 = *(const float4*)(Ap + kc);
        float4 a1 = *(const float4*)(Ap + (size_t)64 * K + kc);
        float4 b0 = *(const float4*)(Bp + kc);
        float4 b1 = *(const float4*)(Bp + (size_t)64 * K + kc);
        __syncthreads();
        As[kq + 0][r] = a0.x; As[kq + 1][r] = a0.y; As[kq + 2][r] = a0.z; As[kq + 3][r] = a0.w;
        As[kq + 0][r + 64] = a1.x; As[kq + 1][r + 64] = a1.y; As[kq + 2][r + 64] = a1.z; As[kq + 3][r + 64] = a1.w;
        Bs[kq + 0][r] = b0.x; Bs[kq + 1][r] = b0.y; Bs[kq + 2][r] = b0.z; Bs[kq + 3][r] = b0.w;
        Bs[kq + 0][r + 64] = b1.x; Bs[kq + 1][r + 64] = b1.y; Bs[kq + 2][r + 64] = b1.z; Bs[kq + 3][r + 64] = b1.w;
        __syncthreads();
#pragma unroll
        for (int k = 0; k < 16; ++k) {
            float4 av0 = *(const float4*)&As[k][ty * 4];
            float4 av1 = *(const float4*)&As[k][ty * 4 + 64];
            float4 bv0 = *(const float4*)&Bs[k][tx * 4];
            float4 bv1 = *(const float4*)&Bs[k][tx * 4 + 64];
            float a[8] = {av0.x, av0.y, av0.z, av0.w, av1.x, av1.y, av1.z, av1.w};
            float b[8] = {bv0.x, bv0.y, bv0.z, bv0.w, bv1.x, bv1.y, bv1.z, bv1.w};
#pragma unroll
            for (int i = 0; i < 8; ++i)
#pragma unroll
                for (int j = 0; j < 8; ++j)
                    acc[i][j] = fmaf(a[i], b[j], acc[i][j]);
        }
    }

    float bl[8] = {0, 0, 0, 0, 0, 0, 0, 0};
    if (bias) {
        float4 t0 = *(const float4*)&bias[n0 + tx * 4];
        float4 t1 = *(const float4*)&bias[n0 + tx * 4 + 64];
        bl[0] = t0.x; bl[1] = t0.y; bl[2] = t0.z; bl[3] = t0.w;
        bl[4] = t1.x; bl[5] = t1.y; bl[6] = t1.z; bl[7] = t1.w;
    }
#pragma unroll
    for (int i = 0; i < 8; ++i) {
        int m = m0 + ty * 4 + (i < 4 ? i : 64 + (i - 4));
        float4 w0, w1;
        w0.x = (acc[i][0] + bl[0]) * scale;
        w0.y = (acc[i][1] + bl[1]) * scale;
        w0.z = (acc[i][2] + bl[2]) * scale;
        w0.w = (acc[i][3] + bl[3]) * scale;
        w1.x = (acc[i][4] + bl[4]) * scale;
        w1.y = (acc[i][5] + bl[5]) * scale;
        w1.z = (acc[i][6] + bl[6]) * scale;
        w1.w = (acc[i][7] + bl[7]) * scale;
        *(float4*)&Cout[(size_t)m * N + n0 + tx * 4] = w0;
        *(float4*)&Cout[(size_t)m * N + n0 + tx * 4 + 64] = w1;
    }
}

// block: (b, group of 4 l's, chunk of 256 c's). wave handles 64 c's serially,
// lanes hold 8 d-slices (d = lane*4..lane*4+3 and 256+lane*4..+3).
__global__ __launch_bounds__(256) void fused_align_kernel(
    const float* __restrict__ wq_s,   // [512][512], pre-scaled by 2*log2e
    const float* __restrict__ uc_s,   // [4096][512], pre-scaled
    const float* __restrict__ Vv,     // [512], raw
    float* __restrict__ out_align)    // [512][1024]
{
    const int bid  = blockIdx.x;
    const int b    = bid >> 7;
    const int rem  = bid & 127;
    const int l4   = rem >> 2;
    const int cq   = rem & 3;
    const int wave = threadIdx.x >> 6;
    const int lane = threadIdx.x & 63;
    const int cbase = cq * 256 + wave * 64;
    const int dlo = lane * 4, dhi = 256 + lane * 4;

    float4 wq0[4], wq1[4];
#pragma unroll
    for (int li = 0; li < 4; ++li) {
        const float* p = wq_s + (size_t)(b * 128 + l4 * 4 + li) * DD;
        wq0[li] = *(const float4*)(p + dlo);
        wq1[li] = *(const float4*)(p + dhi);
    }
    const float4 v0 = *(const float4*)(Vv + dlo);
    const float4 v1 = *(const float4*)(Vv + dhi);
    // p starts at -0.5*sum(V_lane): align = -2*sum_d V_d*(r_d - 0.5) = sum V_d*(1-2 r_d)
    const float pinit = -0.5f * (v0.x + v0.y + v0.z + v0.w + v1.x + v1.y + v1.z + v1.w);

    float outv[4] = {0, 0, 0, 0};
    const float* ucb = uc_s + (size_t)(b * 1024 + cbase) * DD;

    for (int i = 0; i < 64; ++i) {
        const float* up = ucb + (size_t)i * DD;
        float4 u0 = *(const float4*)(up + dlo);
        float4 u1 = *(const float4*)(up + dhi);
#pragma unroll
        for (int li = 0; li < 4; ++li) {
            float p = pinit;
            p = fmaf(v0.x, tanh_term(wq0[li].x + u0.x), p);
            p = fmaf(v0.y, tanh_term(wq0[li].y + u0.y), p);
            p = fmaf(v0.z, tanh_term(wq0[li].z + u0.z), p);
            p = fmaf(v0.w, tanh_term(wq0[li].w + u0.w), p);
            p = fmaf(v1.x, tanh_term(wq1[li].x + u1.x), p);
            p = fmaf(v1.y, tanh_term(wq1[li].y + u1.y), p);
            p = fmaf(v1.z, tanh_term(wq1[li].z + u1.z), p);
            p = fmaf(v1.w, tanh_term(wq1[li].w + u1.w), p);
#pragma unroll
            for (int m = 32; m >= 1; m >>= 1) p += __shfl_xor(p, m, 64);
            float val = -2.0f * p;
            outv[li] = (lane == i) ? val : outv[li];
        }
    }
#pragma unroll
    for (int li = 0; li < 4; ++li)
        out_align[(size_t)(b * 128 + l4 * 4 + li) * 1024 + cbase + lane] = outv[li];
}

// in-place softmax over rows of 1024; one wave per row
__global__ __launch_bounds__(256) void softmax_kernel(float* __restrict__ data)
{
    const int row  = blockIdx.x * 4 + (threadIdx.x >> 6);
    const int lane = threadIdx.x & 63;
    float* p = data + (size_t)row * 1024;

    float4 x[4];
#pragma unroll
    for (int j = 0; j < 4; ++j) x[j] = *(const float4*)(p + j * 256 + lane * 4);

    float m = x[0].x;
#pragma unroll
    for (int j = 0; j < 4; ++j) {
        m = fmaxf(m, x[j].x); m = fmaxf(m, x[j].y);
        m = fmaxf(m, x[j].z); m = fmaxf(m, x[j].w);
    }
#pragma unroll
    for (int mask = 32; mask >= 1; mask >>= 1) m = fmaxf(m, __shfl_xor(m, mask, 64));

    const float LOG2E = 1.4426950408889634f;
    float s = 0.0f;
#pragma unroll
    for (int j = 0; j < 4; ++j) {
        x[j].x = __builtin_amdgcn_exp2f((x[j].x - m) * LOG2E);
        x[j].y = __builtin_amdgcn_exp2f((x[j].y - m) * LOG2E);
        x[j].z = __builtin_amdgcn_exp2f((x[j].z - m) * LOG2E);
        x[j].w = __builtin_amdgcn_exp2f((x[j].w - m) * LOG2E);
        s += x[j].x + x[j].y + x[j].z + x[j].w;
    }
#pragma unroll
    for (int mask = 32; mask >= 1; mask >>= 1) s += __shfl_xor(s, mask, 64);
    const float r = __builtin_amdgcn_rcpf(s);
#pragma unroll
    for (int j = 0; j < 4; ++j) {
        x[j].x *= r; x[j].y *= r; x[j].z *= r; x[j].w *= r;
        *(float4*)(p + j * 256 + lane * 4) = x[j];
    }
}

extern "C" void kernel_launch(void* const* d_in, const int* in_sizes, int n_in,
                              void* d_out, int out_size, void* d_ws, size_t ws_size,
                              hipStream_t stream)
{
    const float* hidden = (const float*)d_in[0];  // [4,128,512]
    const float* ctx    = (const float*)d_in[1];  // [4,1024,512]
    const float* W      = (const float*)d_in[2];  // [512,512]
    const float* U      = (const float*)d_in[3];  // [512,512]
    const float* U_b    = (const float*)d_in[4];  // [512]
    const float* V      = (const float*)d_in[5];  // [512]
    float* out = (float*)d_out;                   // [4,128,1024]

    float* wq_s = (float*)d_ws;              // 512*512 floats (1 MB)
    float* uc_s = wq_s + 512 * 512;          // 4096*512 floats (8 MB)

    const float SCALE = 2.8853900817779268f; // 2*log2(e)

    gemm_nt_kernel<<<dim3(4, 4), 256, 0, stream>>>(hidden, W, nullptr, wq_s, 512, 512, 512, SCALE);
    gemm_nt_kernel<<<dim3(4, 32), 256, 0, stream>>>(ctx, U, U_b, uc_s, 4096, 512, 512, SCALE);
    fused_align_kernel<<<512, 256, 0, stream>>>(wq_s, uc_s, V, out);
    softmax_kernel<<<128, 256, 0, stream>>>(out);
}

// Round 2
// 95.055 us; speedup vs baseline: 2.2293x; 2.2293x over previous
//
#include <hip/hip_runtime.h>
#include <hip/hip_bf16.h>

// B=4, L=128, C=1024, D=512, fp32.
// out[b,l,c] = softmax_c( sum_d V[d]*tanh(wq[b,l,d] + uc[b,c,d]) )
// Identity: tanh(x) = 1 - 2/(e^{2x}+1);  e^{2(wq+uc)} = e^{2wq} * e^{2uc}.
// softmax is shift-invariant => drop the constant sum(V) term:
//   align'[b,l,c] = sum_d (-2 V_d) * rcp(ewq[b,d,l]*euc[b,d,c] + 1)
//
// 1) gemm_exp_kernel (one launch, 576 blocks):
//      ewq_t[b][d][l] = exp2(2log2e * (hidden @ W^T))      [4][512][128]
//      euc_t[b][d][c] = exp2(2log2e * (ctx @ U^T + U_b))   [4][512][1024]
// 2) fused_align2: align' -> d_out  (LDS-staged euc tile, lane-local d loop)
// 3) softmax_kernel: in-place row softmax over 1024

#define SCALE2 2.8853900817779268f  // 2*log2(e)

// ---------------------------------------------------------------------------
// Combined GEMM + exp2 + transposed store.
// C_t[b][n][mloc] = exp2(SCALE2*(sum_k A[m][k]*B[n][k] + bias[n]))
// BM=BN=64, K=512, KC=32, 256 threads, 4x4 micro-tile.
// blocks 0..63   : wq  (A=hidden M=512,  Mb=128,  shift=7, bias=null)
// blocks 64..575 : uc  (A=ctx    M=4096, Mb=1024, shift=10, bias=U_b)
// ---------------------------------------------------------------------------
__global__ __launch_bounds__(256) void gemm_exp_kernel(
    const float* __restrict__ hidden, const float* __restrict__ Wm,
    const float* __restrict__ ctx,    const float* __restrict__ Um,
    const float* __restrict__ U_b,
    float* __restrict__ ewq_t, float* __restrict__ euc_t)
{
    __shared__ float As[32][64];
    __shared__ float Bs[32][64];

    int bid = blockIdx.x;
    const float *A, *Bm, *bias;
    float* Ct;
    int m0, n0, mbshift;
    if (bid < 64) {
        A = hidden; Bm = Wm; bias = nullptr; Ct = ewq_t; mbshift = 7;
        m0 = (bid & 7) * 64; n0 = (bid >> 3) * 64;
    } else {
        bid -= 64;
        A = ctx; Bm = Um; bias = U_b; Ct = euc_t; mbshift = 10;
        m0 = (bid & 63) * 64; n0 = (bid >> 6) * 64;
    }
    const int K = 512;
    const int tid = threadIdx.x;
    const int tx = tid & 15, ty = tid >> 4;   // micro-tile coords
    const int lr = tid >> 2;                  // staging row 0..63
    const int lk = (tid & 3) * 8;             // staging k-offset 0,8,16,24

    float acc[4][4];
#pragma unroll
    for (int i = 0; i < 4; ++i)
#pragma unroll
        for (int j = 0; j < 4; ++j) acc[i][j] = 0.0f;

    const float* Ap = A + (size_t)(m0 + lr) * K + lk;
    const float* Bp = Bm + (size_t)(n0 + lr) * K + lk;

    for (int kc = 0; kc < K; kc += 32) {
        float4 a0 = *(const float4*)(Ap + kc);
        float4 a1 = *(const float4*)(Ap + kc + 4);
        float4 b0 = *(const float4*)(Bp + kc);
        float4 b1 = *(const float4*)(Bp + kc + 4);
        __syncthreads();
        As[lk + 0][lr] = a0.x; As[lk + 1][lr] = a0.y; As[lk + 2][lr] = a0.z; As[lk + 3][lr] = a0.w;
        As[lk + 4][lr] = a1.x; As[lk + 5][lr] = a1.y; As[lk + 6][lr] = a1.z; As[lk + 7][lr] = a1.w;
        Bs[lk + 0][lr] = b0.x; Bs[lk + 1][lr] = b0.y; Bs[lk + 2][lr] = b0.z; Bs[lk + 3][lr] = b0.w;
        Bs[lk + 4][lr] = b1.x; Bs[lk + 5][lr] = b1.y; Bs[lk + 6][lr] = b1.z; Bs[lk + 7][lr] = b1.w;
        __syncthreads();
#pragma unroll 16
        for (int k = 0; k < 32; ++k) {
            float4 av = *(const float4*)&As[k][ty * 4];
            float4 bv = *(const float4*)&Bs[k][tx * 4];
            float a[4] = {av.x, av.y, av.z, av.w};
            float b[4] = {bv.x, bv.y, bv.z, bv.w};
#pragma unroll
            for (int i = 0; i < 4; ++i)
#pragma unroll
                for (int j = 0; j < 4; ++j)
                    acc[i][j] = fmaf(a[i], b[j], acc[i][j]);
        }
    }

    float bl[4] = {0, 0, 0, 0};
    if (bias) {
        float4 t = *(const float4*)&bias[n0 + tx * 4];
        bl[0] = t.x; bl[1] = t.y; bl[2] = t.z; bl[3] = t.w;
    }
    const int b   = m0 >> mbshift;
    const int Mb  = 1 << mbshift;
    const int ml0 = (m0 & (Mb - 1)) + ty * 4;
    float* base = Ct + (size_t)b * 512 * Mb;
#pragma unroll
    for (int j = 0; j < 4; ++j) {
        const int n = n0 + tx * 4 + j;
        float4 v;
        v.x = __builtin_amdgcn_exp2f(SCALE2 * (acc[0][j] + bl[j]));
        v.y = __builtin_amdgcn_exp2f(SCALE2 * (acc[1][j] + bl[j]));
        v.z = __builtin_amdgcn_exp2f(SCALE2 * (acc[2][j] + bl[j]));
        v.w = __builtin_amdgcn_exp2f(SCALE2 * (acc[3][j] + bl[j]));
        *(float4*)(base + (size_t)n * Mb + ml0) = v;
    }
}

// ---------------------------------------------------------------------------
// Fused align: block = (b, 64 c's, 16 l's); 4 waves, wave w owns l's l0..l0+3.
// Lane owns c = c0+lane; loops d serially (lane-local reduction, no shuffles).
// ---------------------------------------------------------------------------
__global__ __launch_bounds__(256) void fused_align2(
    const float* __restrict__ ewq_t,  // [4][512][128]
    const float* __restrict__ euc_t,  // [4][512][1024]
    const float* __restrict__ Vv,     // [512]
    float* __restrict__ out)          // [4][128][1024]
{
    __shared__ float uc_s[128][64];   // 32 KB
    __shared__ float wq_s[128][16];   // 8 KB
    const int tid  = threadIdx.x;
    const int lane = tid & 63;
    const int w    = tid >> 6;
    const int c0   = blockIdx.x * 64;   // 16 chunks
    const int lblk = blockIdx.y * 16;   // 8 chunks
    const int b    = blockIdx.z;        // 4

    const float* ucb = euc_t + (size_t)b * 512 * 1024 + c0;
    const float* wqb = ewq_t + (size_t)b * 512 * 128 + lblk;

    float acc0 = 0.f, acc1 = 0.f, acc2 = 0.f, acc3 = 0.f;

    for (int dc = 0; dc < 4; ++dc) {
        __syncthreads();
        {   // stage euc tile [128 d][64 c]
            const float* src = ucb + (size_t)(dc * 128) * 1024;
            const int row = tid >> 4, col = (tid & 15) * 4;
#pragma unroll
            for (int p = 0; p < 8; ++p)
                *(float4*)&uc_s[p * 16 + row][col] =
                    *(const float4*)(src + (size_t)(p * 16 + row) * 1024 + col);
        }
        {   // stage ewq tile [128 d][16 l]
            const float* src = wqb + (size_t)(dc * 128) * 128;
            const int row = tid >> 1, col = (tid & 1) * 8;
            *(float4*)&wq_s[row][col]     = *(const float4*)(src + (size_t)row * 128 + col);
            *(float4*)&wq_s[row][col + 4] = *(const float4*)(src + (size_t)row * 128 + col + 4);
        }
        __syncthreads();

        const float* vp = Vv + dc * 128;
#pragma unroll 16
        for (int d = 0; d < 128; ++d) {
            const float e = uc_s[d][lane];
            const float4 q = *(const float4*)&wq_s[d][w * 4];
            const float vm2 = -2.0f * vp[d];
            const float r0 = __builtin_amdgcn_rcpf(fmaf(q.x, e, 1.0f));
            const float r1 = __builtin_amdgcn_rcpf(fmaf(q.y, e, 1.0f));
            const float r2 = __builtin_amdgcn_rcpf(fmaf(q.z, e, 1.0f));
            const float r3 = __builtin_amdgcn_rcpf(fmaf(q.w, e, 1.0f));
            acc0 = fmaf(vm2, r0, acc0);
            acc1 = fmaf(vm2, r1, acc1);
            acc2 = fmaf(vm2, r2, acc2);
            acc3 = fmaf(vm2, r3, acc3);
        }
    }

    float* op = out + ((size_t)b * 128 + lblk + w * 4) * 1024 + c0 + lane;
    op[0]    = acc0;
    op[1024] = acc1;
    op[2048] = acc2;
    op[3072] = acc3;
}

// in-place softmax over rows of 1024; one wave per row
__global__ __launch_bounds__(256) void softmax_kernel(float* __restrict__ data)
{
    const int row  = blockIdx.x * 4 + (threadIdx.x >> 6);
    const int lane = threadIdx.x & 63;
    float* p = data + (size_t)row * 1024;

    float4 x[4];
#pragma unroll
    for (int j = 0; j < 4; ++j) x[j] = *(const float4*)(p + j * 256 + lane * 4);

    float m = x[0].x;
#pragma unroll
    for (int j = 0; j < 4; ++j) {
        m = fmaxf(m, x[j].x); m = fmaxf(m, x[j].y);
        m = fmaxf(m, x[j].z); m = fmaxf(m, x[j].w);
    }
#pragma unroll
    for (int mask = 32; mask >= 1; mask >>= 1) m = fmaxf(m, __shfl_xor(m, mask, 64));

    const float LOG2E = 1.4426950408889634f;
    float s = 0.0f;
#pragma unroll
    for (int j = 0; j < 4; ++j) {
        x[j].x = __builtin_amdgcn_exp2f((x[j].x - m) * LOG2E);
        x[j].y = __builtin_amdgcn_exp2f((x[j].y - m) * LOG2E);
        x[j].z = __builtin_amdgcn_exp2f((x[j].z - m) * LOG2E);
        x[j].w = __builtin_amdgcn_exp2f((x[j].w - m) * LOG2E);
        s += x[j].x + x[j].y + x[j].z + x[j].w;
    }
#pragma unroll
    for (int mask = 32; mask >= 1; mask >>= 1) s += __shfl_xor(s, mask, 64);
    const float r = __builtin_amdgcn_rcpf(s);
#pragma unroll
    for (int j = 0; j < 4; ++j) {
        x[j].x *= r; x[j].y *= r; x[j].z *= r; x[j].w *= r;
        *(float4*)(p + j * 256 + lane * 4) = x[j];
    }
}

extern "C" void kernel_launch(void* const* d_in, const int* in_sizes, int n_in,
                              void* d_out, int out_size, void* d_ws, size_t ws_size,
                              hipStream_t stream)
{
    const float* hidden = (const float*)d_in[0];  // [4,128,512]
    const float* ctx    = (const float*)d_in[1];  // [4,1024,512]
    const float* W      = (const float*)d_in[2];  // [512,512]
    const float* U      = (const float*)d_in[3];  // [512,512]
    const float* U_b    = (const float*)d_in[4];  // [512]
    const float* V      = (const float*)d_in[5];  // [512]
    float* out = (float*)d_out;                   // [4,128,1024]

    float* ewq_t = (float*)d_ws;                  // [4][512][128]  (1 MB)
    float* euc_t = ewq_t + 4 * 512 * 128;         // [4][512][1024] (8 MB)

    gemm_exp_kernel<<<576, 256, 0, stream>>>(hidden, W, ctx, U, U_b, ewq_t, euc_t);
    fused_align2<<<dim3(16, 8, 4), 256, 0, stream>>>(ewq_t, euc_t, V, out);
    softmax_kernel<<<128, 256, 0, stream>>>(out);
}